// Round 7
// baseline (229.620 us; speedup 1.0000x reference)
//
#include <hip/hip_runtime.h>
#include <hip/hip_bf16.h>

// Problem dims (hardcoded): B=4, S=2048, D=768, H=12, hd=64
//
// Accounting (stable +-3us over 7 rounds): total ~= gemm_qkv + attn +
// gemm_o(~23) + prep(~10) + ~60us fixed (harness memsets/launch gaps).
// R6 finding: every healthy kernel delivers staged bytes at ~6.7-6.8 TB/s
// while HBM FETCH is ~0.4 TB/s -> re-reads are served by Infinity Cache
// (L3) at a ~7 TB/s die ceiling because round-robin block->XCD dispatch
// makes each XCD's resident working set >> 4MB L2. This round: bijective
// XCD-ownership swizzles (c = bid%8) so each XCD's re-read set fits L2.
// gemm_qkv reverted to the proven R3 128x128 2-buffer code (65.7us best;
// R5 depth-2 and R6 256x128 both regressed).
// attn: R0 config proven local optimum (R1/R4 regressed); only the block
// remap added here.
typedef __bf16 bf16;
typedef __bf16 bf16x8 __attribute__((ext_vector_type(8)));
typedef __bf16 bf16x4 __attribute__((ext_vector_type(4)));
typedef short  s16x4  __attribute__((ext_vector_type(4)));
typedef float  f32x4  __attribute__((ext_vector_type(4)));

#if defined(__has_builtin)
#if __has_builtin(__builtin_amdgcn_mfma_f32_16x16x16bf16_1k)
#define HAVE_MFMA16 1
#endif
#if __has_builtin(__builtin_amdgcn_exp2f)
#define EXP2(x) __builtin_amdgcn_exp2f(x)
#else
#define EXP2(x) exp2f(x)
#endif
#else
#define EXP2(x) exp2f(x)
#endif

__device__ __forceinline__ void gl_lds16(const void* g, void* l) {
  __builtin_amdgcn_global_load_lds(
      (__attribute__((address_space(1))) const void*)g,
      (__attribute__((address_space(3))) void*)l, 16, 0, 0);
}

__device__ __forceinline__ f32x4 mfma32(bf16x8 a, bf16x8 b, f32x4 c) {
  return __builtin_amdgcn_mfma_f32_16x16x32_bf16(a, b, c, 0, 0, 0);
}
#if HAVE_MFMA16
__device__ __forceinline__ f32x4 mfma16(s16x4 a, s16x4 b, f32x4 c) {
  return __builtin_amdgcn_mfma_f32_16x16x16bf16_1k(a, b, c, 0, 0, 0);
}
#endif

// ---------------- prep: fp32->bf16 convert (x, W_QKV, W_O) + RoPE trig table
// tab[b*2048+s][d2] = (cos, sin) of pos*theta^(-d2/32).
__global__ void prep(const float* __restrict__ a, bf16* __restrict__ da,
                     const float* __restrict__ b, bf16* __restrict__ db,
                     const float* __restrict__ c, bf16* __restrict__ dc,
                     const int* __restrict__ tpos, const int* __restrict__ thetap,
                     float2* __restrict__ tab) {
  int bx = blockIdx.x;
  if (bx >= 8448) {                       // trig table blocks
    int i = (bx - 8448) * 256 + threadIdx.x; // < 4*2048*32 = 262144
    int d2 = i & 31;
    int bs = i >> 5;                      // b*2048+s
    float lt = log2f((float)(*thetap));
    float fr = exp2f(-(float)d2 * (1.0f / 32.0f) * lt); // theta^(-d2/32)
    float ang = (float)tpos[bs] * fr;
    float sn, cs;
    sincosf(ang, &sn, &cs);
    tab[i] = make_float2(cs, sn);
    return;
  }
  const float* s; bf16* d; int i;
  if (bx < 6144)      { s = a; d = da; i = bx * 256 + threadIdx.x; }
  else if (bx < 7872) { s = b; d = db; i = (bx - 6144) * 256 + threadIdx.x; }
  else                { s = c; d = dc; i = (bx - 7872) * 256 + threadIdx.x; }
  float4 v = ((const float4*)s)[i];
  bf16x4 o;
  o[0] = (bf16)v.x; o[1] = (bf16)v.y; o[2] = (bf16)v.z; o[3] = (bf16)v.w;
  ((bf16x4*)d)[i] = o;
}

// ---------------- GEMM (QKV): C = A[M][K] * B[N][K]^T, K=768, 128x128 tile
// R3-proven 2-buffer skeleton (65.7us). NEW: XCD-ownership block remap.
// Flat grid 1152; c=f%8 (XCD), j=f/8 (0..143): XCD c owns M-panels
// [8c,8c+8), n-column INNER -> per-XCD hot set = ~1 A-panel (196KB) +
// all B (3.5MB) < 4MB L2, vs old round-robin (8 panels + random B = L3
// at the ~7TB/s die ceiling, the R6-identified pole).
// Epilogue: scatter q,k to qkv[mat][b][h][s][64] WITH RoPE (pair partner
// via __shfl_xor(v,1)); Q scaled by 1/sqrt(64)*log2(e). V (mat==2)
// written TRANSPOSED to Vout[b][h][64][2048].
__global__ void gemm_qkv(const bf16* __restrict__ A, const bf16* __restrict__ Bm,
                         bf16* __restrict__ Cout, bf16* __restrict__ Vout,
                         const float2* __restrict__ tab) {
  constexpr int K = 768;
  __shared__ __align__(16) char As[2][128 * 64]; // 128 rows x 32 bf16/buf, swizzled
  __shared__ __align__(16) char Bs[2][128 * 64];
  const int tid = threadIdx.x;
  const int w = tid >> 6, lane = tid & 63;
  const int quad = lane >> 4, l15 = lane & 15;
  const int wrow = w >> 1, wcol = w & 1;
  const int f = blockIdx.x;                 // 0..1151
  const int xcd = f & 7, j = f >> 3;        // j 0..143 = 8 mtiles x 18 ncols
  const int m0 = (xcd * 8 + j / 18) * 128;  // XCD-owned M-panel, n-inner
  const int n0 = (j % 18) * 128;

  f32x4 acc[4][4];
#pragma unroll
  for (int mt = 0; mt < 4; ++mt)
#pragma unroll
    for (int nt = 0; nt < 4; ++nt) acc[mt][nt] = (f32x4){0.f, 0.f, 0.f, 0.f};

  auto stage = [&](int k0, int bufi) {
#pragma unroll
    for (int i = 0; i < 2; ++i) {
      int L = i * 256 + tid;          // chunk index 0..511
      int r = L >> 2, cl = L & 3;
      int cg = cl ^ ((r >> 1) & 3);   // swizzle: conflict-free frag reads
      gl_lds16(A + (size_t)(m0 + r) * K + k0 + cg * 8, As[bufi] + (i * 256 + w * 64) * 16);
      gl_lds16(Bm + (size_t)(n0 + r) * K + k0 + cg * 8, Bs[bufi] + (i * 256 + w * 64) * 16);
    }
  };

  stage(0, 0);
  int buf = 0;

  for (int k0 = 0; k0 < K; k0 += 32) {
    __syncthreads();                 // drains stage(k0) (issued last iter)
    if (k0 + 32 < K) stage(k0 + 32, buf ^ 1);
    const char* Ab = As[buf];
    const char* Bb = Bs[buf];

    bf16x8 af[4], bfr[4];
#pragma unroll
    for (int mt = 0; mt < 4; ++mt) {
      int r = wrow * 64 + mt * 16 + l15;
      int cl = quad ^ ((r >> 1) & 3);
      af[mt] = *(const bf16x8*)(Ab + r * 64 + cl * 16);
    }
#pragma unroll
    for (int nt = 0; nt < 4; ++nt) {
      int r = wcol * 64 + nt * 16 + l15;
      int cl = quad ^ ((r >> 1) & 3);
      bfr[nt] = *(const bf16x8*)(Bb + r * 64 + cl * 16);
    }
#pragma unroll
    for (int mt = 0; mt < 4; ++mt)
#pragma unroll
      for (int nt = 0; nt < 4; ++nt)
        acc[mt][nt] = mfma32(af[mt], bfr[nt], acc[mt][nt]);
    buf ^= 1;
  }

#pragma unroll
  for (int mt = 0; mt < 4; ++mt)
#pragma unroll
    for (int nt = 0; nt < 4; ++nt)
#pragma unroll
      for (int r = 0; r < 4; ++r) {
        int m = m0 + wrow * 64 + mt * 16 + quad * 4 + r;
        int n = n0 + wcol * 64 + nt * 16 + l15;
        float v = acc[mt][nt][r];
        int mat = n / 768, rem = n % 768;   // mat is block-uniform (768 % 128 == 0)
        int hh = rem >> 6, d = rem & 63;
        int bb = m >> 11, s = m & 2047;
        if (mat == 2) {
          Vout[(((size_t)(bb * 12 + hh) * 64 + d) * 2048) + s] = (bf16)v;
        } else {
          // RoPE: pair partner lives in the adjacent lane (d^1).
          float partner = __shfl_xor(v, 1);
          float2 t = tab[((size_t)m << 5) + ((rem >> 1) & 31)]; // (cos, sin)
          float out = v * t.x + ((n & 1) ? partner : -partner) * t.y;
          if (mat == 0) out *= 0.18033688011112042f; // 1/sqrt(64)*log2(e)
          Cout[(((size_t)(mat * 4 + bb) * 12 + hh) * 2048 + s) * 64 + d] = (bf16)out;
        }
      }
}

// ---------------- GEMM (output proj): C[M][N] = A[M][K]*B[N][K]^T, fp32 out
// 64x128 tile, flat grid 768 with XCD-ownership remap: XCD c owns 16
// M-tiles, y-inner; B (1.2MB) L2-resident per XCD.
__global__ __launch_bounds__(256, 4)
void gemm_o(const bf16* __restrict__ A, const bf16* __restrict__ Bm,
            float* __restrict__ Cout) {
  constexpr int K = 768;
  __shared__ __align__(16) char As[2][64 * 64];  // 64 rows x 32 bf16, swizzled
  __shared__ __align__(16) char Bs[2][128 * 64]; // 128 rows x 32 bf16, swizzled
  const int tid = threadIdx.x;
  const int w = tid >> 6, lane = tid & 63;
  const int quad = lane >> 4, l15 = lane & 15;
  const int wrow = w >> 1, wcol = w & 1;
  const int f = blockIdx.x;                 // 0..767
  const int xcd = f & 7, j = f >> 3;        // j 0..95 = 16 mtiles x 6 ncols
  const int m0 = (xcd * 16 + j / 6) * 64;
  const int n0 = (j % 6) * 128;

  f32x4 acc[2][4];
#pragma unroll
  for (int mt = 0; mt < 2; ++mt)
#pragma unroll
    for (int nt = 0; nt < 4; ++nt) acc[mt][nt] = (f32x4){0.f, 0.f, 0.f, 0.f};

  auto stage = [&](int k0, int bufi) {
    {
      int L = tid;                    // A: 256 chunks (64 rows x 4)
      int r = L >> 2, cl = L & 3;
      int cg = cl ^ ((r >> 1) & 3);
      gl_lds16(A + (size_t)(m0 + r) * K + k0 + cg * 8, As[bufi] + (w * 64) * 16 + lane * 16);
    }
#pragma unroll
    for (int i = 0; i < 2; ++i) {     // B: 512 chunks (128 rows x 4)
      int L = i * 256 + tid;
      int r = L >> 2, cl = L & 3;
      int cg = cl ^ ((r >> 1) & 3);
      gl_lds16(Bm + (size_t)(n0 + r) * K + k0 + cg * 8, Bs[bufi] + (i * 256 + w * 64) * 16);
    }
  };

  stage(0, 0);
  int buf = 0;

  for (int k0 = 0; k0 < K; k0 += 32) {
    __syncthreads();
    if (k0 + 32 < K) stage(k0 + 32, buf ^ 1);
    const char* Ab = As[buf];
    const char* Bb = Bs[buf];

    bf16x8 af[2], bfr[4];
#pragma unroll
    for (int mt = 0; mt < 2; ++mt) {
      int r = wrow * 32 + mt * 16 + l15;
      int cl = quad ^ ((r >> 1) & 3);
      af[mt] = *(const bf16x8*)(Ab + r * 64 + cl * 16);
    }
#pragma unroll
    for (int nt = 0; nt < 4; ++nt) {
      int r = wcol * 64 + nt * 16 + l15;
      int cl = quad ^ ((r >> 1) & 3);
      bfr[nt] = *(const bf16x8*)(Bb + r * 64 + cl * 16);
    }
#pragma unroll
    for (int mt = 0; mt < 2; ++mt)
#pragma unroll
      for (int nt = 0; nt < 4; ++nt)
        acc[mt][nt] = mfma32(af[mt], bfr[nt], acc[mt][nt]);
    buf ^= 1;
  }

#pragma unroll
  for (int mt = 0; mt < 2; ++mt)
#pragma unroll
    for (int nt = 0; nt < 4; ++nt)
#pragma unroll
      for (int r = 0; r < 4; ++r) {
        int m = m0 + wrow * 32 + mt * 16 + quad * 4 + r;
        int n = n0 + wcol * 64 + nt * 16 + l15;
        Cout[(size_t)m * 768 + n] = acc[mt][nt][r];
      }
}

// ---------------- Flash attention (causal), 64 q/block, 2 waves ----
// R0-measured 60us compute structure, verbatim. NEW: XCD-ownership
// remap — XCD c owns 6 (b,h) pairs (K/V working set 6x512KB = 3MB < 4MB
// L2), qt-outer longest-first / bh-inner. Old round-robin spread all 48
// K/V streams (24MB) across every XCD -> L3-served at the ~7TB/s pole.
__global__ __launch_bounds__(128, 3)
void attn(const bf16* __restrict__ qkv, const bf16* __restrict__ vt,
          bf16* __restrict__ aout) {
  const int bx = blockIdx.x;                // 0..1535
  const int xcd = bx & 7, jb = bx >> 3;     // jb 0..191 = 32 qtiles x 6 bh
  const int qt = 31 - (jb / 6);             // longest-first within each XCD
  const int bh = xcd * 6 + (jb % 6);        // XCD-owned (b,h) group
  const int b = bh / 12, h = bh % 12;
  const int tid = threadIdx.x, w = tid >> 6, lane = tid & 63;
  const int quad = lane >> 4, l15 = lane & 15;
  const bf16* Q  = qkv + (size_t)bh * (2048 * 64);
  const bf16* Kp = qkv + (size_t)(48 + bh) * (2048 * 64);
  const bf16* Vt = vt + (size_t)bh * (64 * 2048);
  __shared__ __align__(16) char Ks[2][64 * 128]; // 64 keys x 64 d, swizzled chunks
  __shared__ __align__(16) char Vs[2][64 * 128]; // 64 d x 64 keys, swizzled chunks

  const int qbase = qt * 64 + w * 32; // wave's 32 queries: [qbase, qbase+32)
  bf16x8 qf[2][2];
#pragma unroll
  for (int j = 0; j < 2; ++j) {
    qf[j][0] = *(const bf16x8*)(Q + (size_t)(qbase + j * 16 + l15) * 64 + quad * 8);
    qf[j][1] = *(const bf16x8*)(Q + (size_t)(qbase + j * 16 + l15) * 64 + 32 + quad * 8);
  }

  float li[2] = {0.f, 0.f};
  f32x4 o[2][4];
#pragma unroll
  for (int j = 0; j < 2; ++j)
#pragma unroll
    for (int dt = 0; dt < 4; ++dt) o[j][dt] = (f32x4){0.f, 0.f, 0.f, 0.f};

  // stage K/V tile kb into LDS buffer bufi (async; drained by next barrier)
  auto stage = [&](int kb, int bufi) {
#pragma unroll
    for (int i = 0; i < 4; ++i) {
      int L = i * 128 + tid;          // chunk 0..511; lds dest = base + lane*16
      int r = L >> 3, cl = L & 7, cg = cl ^ (r & 7);
      gl_lds16(Kp + (size_t)(kb * 64 + r) * 64 + cg * 8, Ks[bufi] + L * 16);
      gl_lds16(Vt + (size_t)r * 2048 + kb * 64 + cg * 8, Vs[bufi] + L * 16);
    }
  };

  stage(0, 0);
  int buf = 0;

  for (int kb = 0; kb <= qt; ++kb) {
    __syncthreads();               // drains vmcnt: tile kb resident, buf^1 free
    if (kb < qt) stage(kb + 1, buf ^ 1);
    const char* Kb = Ks[buf];
    const char* Vb = Vs[buf];

    // S^T tiles: lane holds S[query=qbase+j*16+l15][key=kb*64+sk*16+quad*4+rr]
    float S[2][16];
#pragma unroll
    for (int sk = 0; sk < 4; ++sk) {
      int r = sk * 16 + l15;
      int cl0 = quad ^ (r & 7);
      int cl1 = (4 + quad) ^ (r & 7);
      bf16x8 kf0 = *(const bf16x8*)(Kb + r * 128 + cl0 * 16);
      bf16x8 kf1 = *(const bf16x8*)(Kb + r * 128 + cl1 * 16);
#pragma unroll
      for (int j = 0; j < 2; ++j) {
        f32x4 st = (f32x4){0.f, 0.f, 0.f, 0.f};
        st = mfma32(kf0, qf[j][0], st);
        st = mfma32(kf1, qf[j][1], st);
#pragma unroll
        for (int rr = 0; rr < 4; ++rr) S[j][sk * 4 + rr] = st[rr]; // pre-scaled via Q
      }
    }
    if (kb == qt) { // diagonal tile: mask future keys
#pragma unroll
      for (int j = 0; j < 2; ++j)
#pragma unroll
        for (int sk = 0; sk < 4; ++sk)
#pragma unroll
          for (int rr = 0; rr < 4; ++rr) {
            int key = kb * 64 + sk * 16 + quad * 4 + rr;
            if (key > qbase + j * 16 + l15) S[j][sk * 4 + rr] = -1e30f;
          }
    }

#if HAVE_MFMA16
    s16x4 pf[2][4];
#endif
#pragma unroll
    for (int j = 0; j < 2; ++j) {
      float rs = 0.f;
#pragma unroll
      for (int sk = 0; sk < 4; ++sk) {
        bf16x4 pb;
#pragma unroll
        for (int rr = 0; rr < 4; ++rr) {
          float p = EXP2(S[j][sk * 4 + rr]);
          rs += p;
          pb[rr] = (bf16)p;
#if !HAVE_MFMA16
          S[j][sk * 4 + rr] = p;
#endif
        }
#if HAVE_MFMA16
        pf[j][sk] = __builtin_bit_cast(s16x4, pb);
#else
        (void)pb;
#endif
      }
      rs += __shfl_xor(rs, 16);
      rs += __shfl_xor(rs, 32);
      li[j] += rs;
    }

#if HAVE_MFMA16
    // P C/D layout == A-operand layout of 16x16x16: direct feed; V-frag
    // LDS reads shared across both q-subtiles.
#pragma unroll
    for (int sk = 0; sk < 4; ++sk)
#pragma unroll
      for (int dt = 0; dt < 4; ++dt) {
        int rr = dt * 16 + l15;                 // Vt row (d)
        int c = sk * 2 + (quad >> 1);           // 16B chunk along keys
        int cl = c ^ (rr & 7);
        s16x4 vf = *(const s16x4*)(Vb + rr * 128 + cl * 16 + (quad & 1) * 8);
        o[0][dt] = mfma16(pf[0][sk], vf, o[0][dt]);
        o[1][dt] = mfma16(pf[1][sk], vf, o[1][dt]);
      }
#else
    // Fallback: assemble A-frags for 16x16x32 PV via shuffles
#pragma unroll
    for (int j = 0; j < 2; ++j)
#pragma unroll
      for (int kc = 0; kc < 2; ++kc) {
        bf16x8 af;
#pragma unroll
        for (int jj = 0; jj < 8; ++jj) {
          int sq = (quad & 1) * 2 + (jj >> 2);
          int src = sq * 16 + l15;
          float v0 = __shfl(S[j][kc * 8 + (jj & 3)], src);
          float v1 = __shfl(S[j][kc * 8 + 4 + (jj & 3)], src);
          af[jj] = (bf16)((quad < 2) ? v0 : v1);
        }
#pragma unroll
        for (int dt = 0; dt < 4; ++dt) {
          int rr = dt * 16 + l15;
          int c = kc * 4 + quad;
          int cl = c ^ (rr & 7);
          bf16x8 vf = *(const bf16x8*)(Vb + rr * 128 + cl * 16);
          o[j][dt] = mfma32(af, vf, o[j][dt]);
        }
      }
#endif
    buf ^= 1;
  }

#pragma unroll
  for (int j = 0; j < 2; ++j) {
    float lr[4];
#pragma unroll
    for (int rr = 0; rr < 4; ++rr)
      lr[rr] = __builtin_amdgcn_rcpf(__shfl(li[j], quad * 4 + rr));
#pragma unroll
    for (int dt = 0; dt < 4; ++dt)
#pragma unroll
      for (int rr = 0; rr < 4; ++rr) {
        int q = qbase + j * 16 + quad * 4 + rr;
        int n = h * 64 + dt * 16 + l15;
        aout[((size_t)b * 2048 + q) * 768 + n] = (bf16)(o[j][dt][rr] * lr[rr]);
      }
  }
}

// ---------------- launch ----------------
extern "C" void kernel_launch(void* const* d_in, const int* in_sizes, int n_in,
                              void* d_out, int out_size, void* d_ws, size_t ws_size,
                              hipStream_t stream) {
  const float* x    = (const float*)d_in[0];
  const float* wqkv = (const float*)d_in[1];
  const float* wo   = (const float*)d_in[2];
  const int* tpos   = (const int*)d_in[3];
  const int* thetap = (const int*)d_in[5];

  char* ws = (char*)d_ws;
  // ws layout (bytes):
  bf16* xb    = (bf16*)(ws);              // 12,582,912  (reused as attn out)
  bf16* wqkvb = (bf16*)(ws + 12582912);   //  3,538,944
  bf16* wob   = (bf16*)(ws + 16121856);   //  1,179,648
  bf16* qkv   = (bf16*)(ws + 17301504);   // 37,748,736  [3][b][h][s][64] (mat==2 slot unused)
  bf16* vtb   = (bf16*)(ws + 55050240);   // 12,582,912  [b][h][64][2048]
  float2* tab = (float2*)(ws + 42467328); //  2,097,152  trig table, inside unused qkv mat==2 slot

  prep<<<9472, 256, 0, stream>>>(x, xb, wqkv, wqkvb, wo, wob, tpos, thetap, tab);
  gemm_qkv<<<1152, 256, 0, stream>>>(xb, wqkvb, qkv, vtb, tab);
  attn<<<1536, 128, 0, stream>>>(qkv, vtb, xb);
  gemm_o<<<768, 256, 0, stream>>>(xb, wob, (float*)d_out);
}

// Round 8
// 219.996 us; speedup vs baseline: 1.0437x; 1.0437x over previous
//
#include <hip/hip_runtime.h>
#include <hip/hip_bf16.h>

// Problem dims (hardcoded): B=4, S=2048, D=768, H=12, hd=64
//
// Accounting: total ~= gemm_qkv + attn + gemm_o + prep(~10) + ~60us fixed.
// R7 split result: XCD-ownership remap HELPED attn (~60 -> ~30, K/V set
// 3MB/XCD fits L2 — R6 theory validated) but HURT gemm_qkv (65.7 -> 108:
// the default x-fastest 2D grid was ALREADY L2-friendly [8 m-tiles share
// each B-panel per XCD, ~3.5MB]; n-inner ownership cycled all 18 B-panels
// concurrently and broke write-combining, WRITE 37->53MB).
// This round: gemm_qkv reverted to proven R3 (64,18) grid; attn & gemm_o
// keep their R7 remaps. attn compute structure: R0 local optimum.
typedef __bf16 bf16;
typedef __bf16 bf16x8 __attribute__((ext_vector_type(8)));
typedef __bf16 bf16x4 __attribute__((ext_vector_type(4)));
typedef short  s16x4  __attribute__((ext_vector_type(4)));
typedef float  f32x4  __attribute__((ext_vector_type(4)));

#if defined(__has_builtin)
#if __has_builtin(__builtin_amdgcn_mfma_f32_16x16x16bf16_1k)
#define HAVE_MFMA16 1
#endif
#if __has_builtin(__builtin_amdgcn_exp2f)
#define EXP2(x) __builtin_amdgcn_exp2f(x)
#else
#define EXP2(x) exp2f(x)
#endif
#else
#define EXP2(x) exp2f(x)
#endif

__device__ __forceinline__ void gl_lds16(const void* g, void* l) {
  __builtin_amdgcn_global_load_lds(
      (__attribute__((address_space(1))) const void*)g,
      (__attribute__((address_space(3))) void*)l, 16, 0, 0);
}

__device__ __forceinline__ f32x4 mfma32(bf16x8 a, bf16x8 b, f32x4 c) {
  return __builtin_amdgcn_mfma_f32_16x16x32_bf16(a, b, c, 0, 0, 0);
}
#if HAVE_MFMA16
__device__ __forceinline__ f32x4 mfma16(s16x4 a, s16x4 b, f32x4 c) {
  return __builtin_amdgcn_mfma_f32_16x16x16bf16_1k(a, b, c, 0, 0, 0);
}
#endif

// ---------------- prep: fp32->bf16 convert (x, W_QKV, W_O) + RoPE trig table
// tab[b*2048+s][d2] = (cos, sin) of pos*theta^(-d2/32).
__global__ void prep(const float* __restrict__ a, bf16* __restrict__ da,
                     const float* __restrict__ b, bf16* __restrict__ db,
                     const float* __restrict__ c, bf16* __restrict__ dc,
                     const int* __restrict__ tpos, const int* __restrict__ thetap,
                     float2* __restrict__ tab) {
  int bx = blockIdx.x;
  if (bx >= 8448) {                       // trig table blocks
    int i = (bx - 8448) * 256 + threadIdx.x; // < 4*2048*32 = 262144
    int d2 = i & 31;
    int bs = i >> 5;                      // b*2048+s
    float lt = log2f((float)(*thetap));
    float fr = exp2f(-(float)d2 * (1.0f / 32.0f) * lt); // theta^(-d2/32)
    float ang = (float)tpos[bs] * fr;
    float sn, cs;
    sincosf(ang, &sn, &cs);
    tab[i] = make_float2(cs, sn);
    return;
  }
  const float* s; bf16* d; int i;
  if (bx < 6144)      { s = a; d = da; i = bx * 256 + threadIdx.x; }
  else if (bx < 7872) { s = b; d = db; i = (bx - 6144) * 256 + threadIdx.x; }
  else                { s = c; d = dc; i = (bx - 7872) * 256 + threadIdx.x; }
  float4 v = ((const float4*)s)[i];
  bf16x4 o;
  o[0] = (bf16)v.x; o[1] = (bf16)v.y; o[2] = (bf16)v.z; o[3] = (bf16)v.w;
  ((bf16x4*)d)[i] = o;
}

// ---------------- GEMM (QKV): C = A[M][K] * B[N][K]^T, K=768, 128x128 tile
// R3-proven 65.7us version, restored verbatim: 2D grid (64,18), x=m
// fastest (default dispatch gives each XCD 8 m-tiles sharing each B-panel
// — already ~3.5MB/XCD L2 set; R7's ownership remap regressed to 108us).
// Epilogue: scatter q,k to qkv[mat][b][h][s][64] WITH RoPE (pair partner
// via __shfl_xor(v,1)); Q scaled by 1/sqrt(64)*log2(e). V (mat==2)
// written TRANSPOSED to Vout[b][h][64][2048].
__global__ void gemm_qkv(const bf16* __restrict__ A, const bf16* __restrict__ Bm,
                         bf16* __restrict__ Cout, bf16* __restrict__ Vout,
                         const float2* __restrict__ tab) {
  constexpr int K = 768;
  __shared__ __align__(16) char As[2][128 * 64]; // 128 rows x 32 bf16/buf, swizzled
  __shared__ __align__(16) char Bs[2][128 * 64];
  const int tid = threadIdx.x;
  const int w = tid >> 6, lane = tid & 63;
  const int quad = lane >> 4, l15 = lane & 15;
  const int wrow = w >> 1, wcol = w & 1;
  const int m0 = blockIdx.x * 128, n0 = blockIdx.y * 128;

  f32x4 acc[4][4];
#pragma unroll
  for (int mt = 0; mt < 4; ++mt)
#pragma unroll
    for (int nt = 0; nt < 4; ++nt) acc[mt][nt] = (f32x4){0.f, 0.f, 0.f, 0.f};

  auto stage = [&](int k0, int bufi) {
#pragma unroll
    for (int i = 0; i < 2; ++i) {
      int L = i * 256 + tid;          // chunk index 0..511
      int r = L >> 2, cl = L & 3;
      int cg = cl ^ ((r >> 1) & 3);   // swizzle: conflict-free frag reads
      gl_lds16(A + (size_t)(m0 + r) * K + k0 + cg * 8, As[bufi] + (i * 256 + w * 64) * 16);
      gl_lds16(Bm + (size_t)(n0 + r) * K + k0 + cg * 8, Bs[bufi] + (i * 256 + w * 64) * 16);
    }
  };

  stage(0, 0);
  int buf = 0;

  for (int k0 = 0; k0 < K; k0 += 32) {
    __syncthreads();                 // drains stage(k0) (issued last iter)
    if (k0 + 32 < K) stage(k0 + 32, buf ^ 1);
    const char* Ab = As[buf];
    const char* Bb = Bs[buf];

    bf16x8 af[4], bfr[4];
#pragma unroll
    for (int mt = 0; mt < 4; ++mt) {
      int r = wrow * 64 + mt * 16 + l15;
      int cl = quad ^ ((r >> 1) & 3);
      af[mt] = *(const bf16x8*)(Ab + r * 64 + cl * 16);
    }
#pragma unroll
    for (int nt = 0; nt < 4; ++nt) {
      int r = wcol * 64 + nt * 16 + l15;
      int cl = quad ^ ((r >> 1) & 3);
      bfr[nt] = *(const bf16x8*)(Bb + r * 64 + cl * 16);
    }
#pragma unroll
    for (int mt = 0; mt < 4; ++mt)
#pragma unroll
      for (int nt = 0; nt < 4; ++nt)
        acc[mt][nt] = mfma32(af[mt], bfr[nt], acc[mt][nt]);
    buf ^= 1;
  }

#pragma unroll
  for (int mt = 0; mt < 4; ++mt)
#pragma unroll
    for (int nt = 0; nt < 4; ++nt)
#pragma unroll
      for (int r = 0; r < 4; ++r) {
        int m = m0 + wrow * 64 + mt * 16 + quad * 4 + r;
        int n = n0 + wcol * 64 + nt * 16 + l15;
        float v = acc[mt][nt][r];
        int mat = n / 768, rem = n % 768;   // mat is block-uniform (768 % 128 == 0)
        int hh = rem >> 6, d = rem & 63;
        int bb = m >> 11, s = m & 2047;
        if (mat == 2) {
          Vout[(((size_t)(bb * 12 + hh) * 64 + d) * 2048) + s] = (bf16)v;
        } else {
          // RoPE: pair partner lives in the adjacent lane (d^1).
          float partner = __shfl_xor(v, 1);
          float2 t = tab[((size_t)m << 5) + ((rem >> 1) & 31)]; // (cos, sin)
          float out = v * t.x + ((n & 1) ? partner : -partner) * t.y;
          if (mat == 0) out *= 0.18033688011112042f; // 1/sqrt(64)*log2(e)
          Cout[(((size_t)(mat * 4 + bb) * 12 + hh) * 2048 + s) * 64 + d] = (bf16)out;
        }
      }
}

// ---------------- GEMM (output proj): C[M][N] = A[M][K]*B[N][K]^T, fp32 out
// 64x128 tile, flat grid 768 with XCD-ownership remap (kept from R7: the
// combined attn+gemm_o time dropped ~31us): XCD c owns 16 M-tiles,
// y-inner; B (1.2MB) L2-resident per XCD.
__global__ __launch_bounds__(256, 4)
void gemm_o(const bf16* __restrict__ A, const bf16* __restrict__ Bm,
            float* __restrict__ Cout) {
  constexpr int K = 768;
  __shared__ __align__(16) char As[2][64 * 64];  // 64 rows x 32 bf16, swizzled
  __shared__ __align__(16) char Bs[2][128 * 64]; // 128 rows x 32 bf16, swizzled
  const int tid = threadIdx.x;
  const int w = tid >> 6, lane = tid & 63;
  const int quad = lane >> 4, l15 = lane & 15;
  const int wrow = w >> 1, wcol = w & 1;
  const int f = blockIdx.x;                 // 0..767
  const int xcd = f & 7, j = f >> 3;        // j 0..95 = 16 mtiles x 6 ncols
  const int m0 = (xcd * 16 + j / 6) * 64;
  const int n0 = (j % 6) * 128;

  f32x4 acc[2][4];
#pragma unroll
  for (int mt = 0; mt < 2; ++mt)
#pragma unroll
    for (int nt = 0; nt < 4; ++nt) acc[mt][nt] = (f32x4){0.f, 0.f, 0.f, 0.f};

  auto stage = [&](int k0, int bufi) {
    {
      int L = tid;                    // A: 256 chunks (64 rows x 4)
      int r = L >> 2, cl = L & 3;
      int cg = cl ^ ((r >> 1) & 3);
      gl_lds16(A + (size_t)(m0 + r) * K + k0 + cg * 8, As[bufi] + (w * 64) * 16 + lane * 16);
    }
#pragma unroll
    for (int i = 0; i < 2; ++i) {     // B: 512 chunks (128 rows x 4)
      int L = i * 256 + tid;
      int r = L >> 2, cl = L & 3;
      int cg = cl ^ ((r >> 1) & 3);
      gl_lds16(Bm + (size_t)(n0 + r) * K + k0 + cg * 8, Bs[bufi] + (i * 256 + w * 64) * 16);
    }
  };

  stage(0, 0);
  int buf = 0;

  for (int k0 = 0; k0 < K; k0 += 32) {
    __syncthreads();
    if (k0 + 32 < K) stage(k0 + 32, buf ^ 1);
    const char* Ab = As[buf];
    const char* Bb = Bs[buf];

    bf16x8 af[2], bfr[4];
#pragma unroll
    for (int mt = 0; mt < 2; ++mt) {
      int r = wrow * 32 + mt * 16 + l15;
      int cl = quad ^ ((r >> 1) & 3);
      af[mt] = *(const bf16x8*)(Ab + r * 64 + cl * 16);
    }
#pragma unroll
    for (int nt = 0; nt < 4; ++nt) {
      int r = wcol * 64 + nt * 16 + l15;
      int cl = quad ^ ((r >> 1) & 3);
      bfr[nt] = *(const bf16x8*)(Bb + r * 64 + cl * 16);
    }
#pragma unroll
    for (int mt = 0; mt < 2; ++mt)
#pragma unroll
      for (int nt = 0; nt < 4; ++nt)
        acc[mt][nt] = mfma32(af[mt], bfr[nt], acc[mt][nt]);
    buf ^= 1;
  }

#pragma unroll
  for (int mt = 0; mt < 2; ++mt)
#pragma unroll
    for (int nt = 0; nt < 4; ++nt)
#pragma unroll
      for (int r = 0; r < 4; ++r) {
        int m = m0 + wrow * 32 + mt * 16 + quad * 4 + r;
        int n = n0 + wcol * 64 + nt * 16 + l15;
        Cout[(size_t)m * 768 + n] = acc[mt][nt][r];
      }
}

// ---------------- Flash attention (causal), 64 q/block, 2 waves ----
// R0-measured compute structure + R7 XCD-ownership remap (kept: ~30us
// improvement, K/V working set 6x512KB = 3MB/XCD fits L2). XCD c owns
// 6 (b,h) pairs, qt-outer longest-first / bh-inner.
__global__ __launch_bounds__(128, 3)
void attn(const bf16* __restrict__ qkv, const bf16* __restrict__ vt,
          bf16* __restrict__ aout) {
  const int bx = blockIdx.x;                // 0..1535
  const int xcd = bx & 7, jb = bx >> 3;     // jb 0..191 = 32 qtiles x 6 bh
  const int qt = 31 - (jb / 6);             // longest-first within each XCD
  const int bh = xcd * 6 + (jb % 6);        // XCD-owned (b,h) group
  const int b = bh / 12, h = bh % 12;
  const int tid = threadIdx.x, w = tid >> 6, lane = tid & 63;
  const int quad = lane >> 4, l15 = lane & 15;
  const bf16* Q  = qkv + (size_t)bh * (2048 * 64);
  const bf16* Kp = qkv + (size_t)(48 + bh) * (2048 * 64);
  const bf16* Vt = vt + (size_t)bh * (64 * 2048);
  __shared__ __align__(16) char Ks[2][64 * 128]; // 64 keys x 64 d, swizzled chunks
  __shared__ __align__(16) char Vs[2][64 * 128]; // 64 d x 64 keys, swizzled chunks

  const int qbase = qt * 64 + w * 32; // wave's 32 queries: [qbase, qbase+32)
  bf16x8 qf[2][2];
#pragma unroll
  for (int j = 0; j < 2; ++j) {
    qf[j][0] = *(const bf16x8*)(Q + (size_t)(qbase + j * 16 + l15) * 64 + quad * 8);
    qf[j][1] = *(const bf16x8*)(Q + (size_t)(qbase + j * 16 + l15) * 64 + 32 + quad * 8);
  }

  float li[2] = {0.f, 0.f};
  f32x4 o[2][4];
#pragma unroll
  for (int j = 0; j < 2; ++j)
#pragma unroll
    for (int dt = 0; dt < 4; ++dt) o[j][dt] = (f32x4){0.f, 0.f, 0.f, 0.f};

  // stage K/V tile kb into LDS buffer bufi (async; drained by next barrier)
  auto stage = [&](int kb, int bufi) {
#pragma unroll
    for (int i = 0; i < 4; ++i) {
      int L = i * 128 + tid;          // chunk 0..511; lds dest = base + lane*16
      int r = L >> 3, cl = L & 7, cg = cl ^ (r & 7);
      gl_lds16(Kp + (size_t)(kb * 64 + r) * 64 + cg * 8, Ks[bufi] + L * 16);
      gl_lds16(Vt + (size_t)r * 2048 + kb * 64 + cg * 8, Vs[bufi] + L * 16);
    }
  };

  stage(0, 0);
  int buf = 0;

  for (int kb = 0; kb <= qt; ++kb) {
    __syncthreads();               // drains vmcnt: tile kb resident, buf^1 free
    if (kb < qt) stage(kb + 1, buf ^ 1);
    const char* Kb = Ks[buf];
    const char* Vb = Vs[buf];

    // S^T tiles: lane holds S[query=qbase+j*16+l15][key=kb*64+sk*16+quad*4+rr]
    float S[2][16];
#pragma unroll
    for (int sk = 0; sk < 4; ++sk) {
      int r = sk * 16 + l15;
      int cl0 = quad ^ (r & 7);
      int cl1 = (4 + quad) ^ (r & 7);
      bf16x8 kf0 = *(const bf16x8*)(Kb + r * 128 + cl0 * 16);
      bf16x8 kf1 = *(const bf16x8*)(Kb + r * 128 + cl1 * 16);
#pragma unroll
      for (int j = 0; j < 2; ++j) {
        f32x4 st = (f32x4){0.f, 0.f, 0.f, 0.f};
        st = mfma32(kf0, qf[j][0], st);
        st = mfma32(kf1, qf[j][1], st);
#pragma unroll
        for (int rr = 0; rr < 4; ++rr) S[j][sk * 4 + rr] = st[rr]; // pre-scaled via Q
      }
    }
    if (kb == qt) { // diagonal tile: mask future keys
#pragma unroll
      for (int j = 0; j < 2; ++j)
#pragma unroll
        for (int sk = 0; sk < 4; ++sk)
#pragma unroll
          for (int rr = 0; rr < 4; ++rr) {
            int key = kb * 64 + sk * 16 + quad * 4 + rr;
            if (key > qbase + j * 16 + l15) S[j][sk * 4 + rr] = -1e30f;
          }
    }

#if HAVE_MFMA16
    s16x4 pf[2][4];
#endif
#pragma unroll
    for (int j = 0; j < 2; ++j) {
      float rs = 0.f;
#pragma unroll
      for (int sk = 0; sk < 4; ++sk) {
        bf16x4 pb;
#pragma unroll
        for (int rr = 0; rr < 4; ++rr) {
          float p = EXP2(S[j][sk * 4 + rr]);
          rs += p;
          pb[rr] = (bf16)p;
#if !HAVE_MFMA16
          S[j][sk * 4 + rr] = p;
#endif
        }
#if HAVE_MFMA16
        pf[j][sk] = __builtin_bit_cast(s16x4, pb);
#else
        (void)pb;
#endif
      }
      rs += __shfl_xor(rs, 16);
      rs += __shfl_xor(rs, 32);
      li[j] += rs;
    }

#if HAVE_MFMA16
    // P C/D layout == A-operand layout of 16x16x16: direct feed; V-frag
    // LDS reads shared across both q-subtiles.
#pragma unroll
    for (int sk = 0; sk < 4; ++sk)
#pragma unroll
      for (int dt = 0; dt < 4; ++dt) {
        int rr = dt * 16 + l15;                 // Vt row (d)
        int c = sk * 2 + (quad >> 1);           // 16B chunk along keys
        int cl = c ^ (rr & 7);
        s16x4 vf = *(const s16x4*)(Vb + rr * 128 + cl * 16 + (quad & 1) * 8);
        o[0][dt] = mfma16(pf[0][sk], vf, o[0][dt]);
        o[1][dt] = mfma16(pf[1][sk], vf, o[1][dt]);
      }
#else
    // Fallback: assemble A-frags for 16x16x32 PV via shuffles
#pragma unroll
    for (int j = 0; j < 2; ++j)
#pragma unroll
      for (int kc = 0; kc < 2; ++kc) {
        bf16x8 af;
#pragma unroll
        for (int jj = 0; jj < 8; ++jj) {
          int sq = (quad & 1) * 2 + (jj >> 2);
          int src = sq * 16 + l15;
          float v0 = __shfl(S[j][kc * 8 + (jj & 3)], src);
          float v1 = __shfl(S[j][kc * 8 + 4 + (jj & 3)], src);
          af[jj] = (bf16)((quad < 2) ? v0 : v1);
        }
#pragma unroll
        for (int dt = 0; dt < 4; ++dt) {
          int rr = dt * 16 + l15;
          int c = kc * 4 + quad;
          int cl = c ^ (rr & 7);
          bf16x8 vf = *(const bf16x8*)(Vb + rr * 128 + cl * 16);
          o[j][dt] = mfma32(af, vf, o[j][dt]);
        }
      }
#endif
    buf ^= 1;
  }

#pragma unroll
  for (int j = 0; j < 2; ++j) {
    float lr[4];
#pragma unroll
    for (int rr = 0; rr < 4; ++rr)
      lr[rr] = __builtin_amdgcn_rcpf(__shfl(li[j], quad * 4 + rr));
#pragma unroll
    for (int dt = 0; dt < 4; ++dt)
#pragma unroll
      for (int rr = 0; rr < 4; ++rr) {
        int q = qbase + j * 16 + quad * 4 + rr;
        int n = h * 64 + dt * 16 + l15;
        aout[((size_t)b * 2048 + q) * 768 + n] = (bf16)(o[j][dt][rr] * lr[rr]);
      }
  }
}

// ---------------- launch ----------------
extern "C" void kernel_launch(void* const* d_in, const int* in_sizes, int n_in,
                              void* d_out, int out_size, void* d_ws, size_t ws_size,
                              hipStream_t stream) {
  const float* x    = (const float*)d_in[0];
  const float* wqkv = (const float*)d_in[1];
  const float* wo   = (const float*)d_in[2];
  const int* tpos   = (const int*)d_in[3];
  const int* thetap = (const int*)d_in[5];

  char* ws = (char*)d_ws;
  // ws layout (bytes):
  bf16* xb    = (bf16*)(ws);              // 12,582,912  (reused as attn out)
  bf16* wqkvb = (bf16*)(ws + 12582912);   //  3,538,944
  bf16* wob   = (bf16*)(ws + 16121856);   //  1,179,648
  bf16* qkv   = (bf16*)(ws + 17301504);   // 37,748,736  [3][b][h][s][64] (mat==2 slot unused)
  bf16* vtb   = (bf16*)(ws + 55050240);   // 12,582,912  [b][h][64][2048]
  float2* tab = (float2*)(ws + 42467328); //  2,097,152  trig table, inside unused qkv mat==2 slot

  prep<<<9472, 256, 0, stream>>>(x, xb, wqkv, wqkvb, wo, wob, tpos, thetap, tab);
  gemm_qkv<<<dim3(64, 18), 256, 0, stream>>>(xb, wqkvb, qkv, vtb, tab);
  attn<<<1536, 128, 0, stream>>>(qkv, vtb, xb);
  gemm_o<<<768, 256, 0, stream>>>(xb, wob, (float*)d_out);
}

// Round 9
// 208.579 us; speedup vs baseline: 1.1009x; 1.0547x over previous
//
#include <hip/hip_runtime.h>
#include <hip/hip_bf16.h>

// Problem dims (hardcoded): B=4, S=2048, D=768, H=12, hd=64
//
// Accounting (R8-corrected): total ~= gemm_qkv(66) + attn(60) + gemm_o(~23)
// + prep(~10) + ~61us fixed. Residual is constant ~154 across R3/R5/R6/R8
// -> attn XCD remap NEUTRAL (R7's apparent gain was a profiled-vs-timed
// artifact of the slow remapped gemm_qkv). All cache/schedule levers
// (depth-2, 256-tile, XCD remaps) measured null/negative; both big
// kernels are ~65% pipe-busy plateaus. This round: work-content changes
// only — coalesced V-transpose epilogue (gemm_qkv), occupancy hint,
// attn setprio (m191: +4-7% in this exact regime).
typedef __bf16 bf16;
typedef __bf16 bf16x8 __attribute__((ext_vector_type(8)));
typedef __bf16 bf16x4 __attribute__((ext_vector_type(4)));
typedef short  s16x4  __attribute__((ext_vector_type(4)));
typedef float  f32x4  __attribute__((ext_vector_type(4)));

#if defined(__has_builtin)
#if __has_builtin(__builtin_amdgcn_mfma_f32_16x16x16bf16_1k)
#define HAVE_MFMA16 1
#endif
#if __has_builtin(__builtin_amdgcn_exp2f)
#define EXP2(x) __builtin_amdgcn_exp2f(x)
#else
#define EXP2(x) exp2f(x)
#endif
#else
#define EXP2(x) exp2f(x)
#endif

__device__ __forceinline__ void gl_lds16(const void* g, void* l) {
  __builtin_amdgcn_global_load_lds(
      (__attribute__((address_space(1))) const void*)g,
      (__attribute__((address_space(3))) void*)l, 16, 0, 0);
}

__device__ __forceinline__ f32x4 mfma32(bf16x8 a, bf16x8 b, f32x4 c) {
  return __builtin_amdgcn_mfma_f32_16x16x32_bf16(a, b, c, 0, 0, 0);
}
#if HAVE_MFMA16
__device__ __forceinline__ f32x4 mfma16(s16x4 a, s16x4 b, f32x4 c) {
  return __builtin_amdgcn_mfma_f32_16x16x16bf16_1k(a, b, c, 0, 0, 0);
}
#endif

// ---------------- prep: fp32->bf16 convert (x, W_QKV, W_O) + RoPE trig table
// tab[b*2048+s][d2] = (cos, sin) of pos*theta^(-d2/32).
__global__ void prep(const float* __restrict__ a, bf16* __restrict__ da,
                     const float* __restrict__ b, bf16* __restrict__ db,
                     const float* __restrict__ c, bf16* __restrict__ dc,
                     const int* __restrict__ tpos, const int* __restrict__ thetap,
                     float2* __restrict__ tab) {
  int bx = blockIdx.x;
  if (bx >= 8448) {                       // trig table blocks
    int i = (bx - 8448) * 256 + threadIdx.x; // < 4*2048*32 = 262144
    int d2 = i & 31;
    int bs = i >> 5;                      // b*2048+s
    float lt = log2f((float)(*thetap));
    float fr = exp2f(-(float)d2 * (1.0f / 32.0f) * lt); // theta^(-d2/32)
    float ang = (float)tpos[bs] * fr;
    float sn, cs;
    sincosf(ang, &sn, &cs);
    tab[i] = make_float2(cs, sn);
    return;
  }
  const float* s; bf16* d; int i;
  if (bx < 6144)      { s = a; d = da; i = bx * 256 + threadIdx.x; }
  else if (bx < 7872) { s = b; d = db; i = (bx - 6144) * 256 + threadIdx.x; }
  else                { s = c; d = dc; i = (bx - 7872) * 256 + threadIdx.x; }
  float4 v = ((const float4*)s)[i];
  bf16x4 o;
  o[0] = (bf16)v.x; o[1] = (bf16)v.y; o[2] = (bf16)v.z; o[3] = (bf16)v.w;
  ((bf16x4*)d)[i] = o;
}

// ---------------- GEMM (QKV): C = A[M][K] * B[N][K]^T, K=768, 128x128 tile
// R3-proven 2-buffer skeleton (66us), grid (64,18) default dispatch.
// NEW vs R8: (a) __launch_bounds__(256,4) occupancy request (VGPR 64,
// LDS allows 5 blocks/CU, measured residency was only ~2.5);
// (b) mat==2 (V) blocks transpose their tile through padded LDS and
// store Vout COALESCED (256B segments) instead of 2-byte stores
// scattered across 64 lines/instr (the old V-epilogue was ~64x line
// amplification and made the 6 V-column blocks the stragglers).
// Epilogue q,k: scatter to qkv[mat][b][h][s][64] WITH fused RoPE
// (pair partner via __shfl_xor(v,1)); Q scaled by 1/sqrt(64)*log2(e).
__global__ __launch_bounds__(256, 4)
void gemm_qkv(const bf16* __restrict__ A, const bf16* __restrict__ Bm,
              bf16* __restrict__ Cout, bf16* __restrict__ Vout,
              const float2* __restrict__ tab) {
  constexpr int K = 768;
  // [2 bufs][A 8KB | B 8KB]; also reused (17KB span) by the V-transpose.
  __shared__ __align__(16) char SM[2][16384];
  const int tid = threadIdx.x;
  const int w = tid >> 6, lane = tid & 63;
  const int quad = lane >> 4, l15 = lane & 15;
  const int wrow = w >> 1, wcol = w & 1;
  const int m0 = blockIdx.x * 128, n0 = blockIdx.y * 128;

  f32x4 acc[4][4];
#pragma unroll
  for (int mt = 0; mt < 4; ++mt)
#pragma unroll
    for (int nt = 0; nt < 4; ++nt) acc[mt][nt] = (f32x4){0.f, 0.f, 0.f, 0.f};

  auto stage = [&](int k0, int bufi) {
#pragma unroll
    for (int i = 0; i < 2; ++i) {
      int L = i * 256 + tid;          // chunk index 0..511
      int r = L >> 2, cl = L & 3;
      int cg = cl ^ ((r >> 1) & 3);   // swizzle: conflict-free frag reads
      gl_lds16(A + (size_t)(m0 + r) * K + k0 + cg * 8, SM[bufi] + (i * 256 + w * 64) * 16);
      gl_lds16(Bm + (size_t)(n0 + r) * K + k0 + cg * 8, SM[bufi] + 8192 + (i * 256 + w * 64) * 16);
    }
  };

  stage(0, 0);
  int buf = 0;

  for (int k0 = 0; k0 < K; k0 += 32) {
    __syncthreads();                 // drains stage(k0) (issued last iter)
    if (k0 + 32 < K) stage(k0 + 32, buf ^ 1);
    const char* Ab = SM[buf];
    const char* Bb = SM[buf] + 8192;

    bf16x8 af[4], bfr[4];
#pragma unroll
    for (int mt = 0; mt < 4; ++mt) {
      int r = wrow * 64 + mt * 16 + l15;
      int cl = quad ^ ((r >> 1) & 3);
      af[mt] = *(const bf16x8*)(Ab + r * 64 + cl * 16);
    }
#pragma unroll
    for (int nt = 0; nt < 4; ++nt) {
      int r = wcol * 64 + nt * 16 + l15;
      int cl = quad ^ ((r >> 1) & 3);
      bfr[nt] = *(const bf16x8*)(Bb + r * 64 + cl * 16);
    }
#pragma unroll
    for (int mt = 0; mt < 4; ++mt)
#pragma unroll
      for (int nt = 0; nt < 4; ++nt)
        acc[mt][nt] = mfma32(af[mt], bfr[nt], acc[mt][nt]);
    buf ^= 1;
  }

  const int mat = n0 / 768;            // block-uniform (768 % 128 == 0)
  if (mat == 2) {
    // ---- V: transpose via LDS, coalesced Vout[b][h][64][2048] stores ----
    // T viewed as [64 d][PITCH s] bf16, PITCH=136 (16B-aligned rows,
    // 2-way-free banks). One head at a time (17KB fits in SM).
    constexpr int PITCH = 136;
    bf16* T = (bf16*)&SM[0][0];
    const int bb = m0 >> 11, s0 = m0 & 2047;
    const int hh0 = (n0 % 768) >> 6;   // first of the 2 heads this block covers
#pragma unroll
    for (int hh = 0; hh < 2; ++hh) {
      __syncthreads();                 // LDS free (K-loop / previous head done)
      if (wcol == hh) {                // this wave's acc holds head hh
#pragma unroll
        for (int mt = 0; mt < 4; ++mt)
#pragma unroll
          for (int nt = 0; nt < 4; ++nt)
#pragma unroll
            for (int r = 0; r < 4; ++r) {
              int s_local = wrow * 64 + mt * 16 + quad * 4 + r; // 0..127
              int d_local = nt * 16 + l15;                      // 0..63
              T[d_local * PITCH + s_local] = (bf16)acc[mt][nt][r];
            }
      }
      __syncthreads();
      // read out rows, store coalesced: thread t -> row t>>2, 64B chunk t&3
      {
        int row = tid >> 2, chunk = tid & 3;
        const bf16* src = T + row * PITCH + chunk * 32;
        bf16x8 v0 = ((const bf16x8*)src)[0];
        bf16x8 v1 = ((const bf16x8*)src)[1];
        bf16x8 v2 = ((const bf16x8*)src)[2];
        bf16x8 v3 = ((const bf16x8*)src)[3];
        bf16* dst = Vout + (((size_t)(bb * 12 + hh0 + hh) * 64 + row) * 2048) + s0 + chunk * 32;
        ((bf16x8*)dst)[0] = v0;
        ((bf16x8*)dst)[1] = v1;
        ((bf16x8*)dst)[2] = v2;
        ((bf16x8*)dst)[3] = v3;
      }
    }
  } else {
    // ---- Q/K: RoPE-fused scatter to qkv[mat][b][h][s][64] ----
#pragma unroll
    for (int mt = 0; mt < 4; ++mt)
#pragma unroll
      for (int nt = 0; nt < 4; ++nt)
#pragma unroll
        for (int r = 0; r < 4; ++r) {
          int m = m0 + wrow * 64 + mt * 16 + quad * 4 + r;
          int n = n0 + wcol * 64 + nt * 16 + l15;
          float v = acc[mt][nt][r];
          int rem = n % 768;
          int hh = rem >> 6, d = rem & 63;
          int bb = m >> 11, s = m & 2047;
          // RoPE: pair partner lives in the adjacent lane (d^1).
          float partner = __shfl_xor(v, 1);
          float2 t = tab[((size_t)m << 5) + ((rem >> 1) & 31)]; // (cos, sin)
          float out = v * t.x + ((n & 1) ? partner : -partner) * t.y;
          if (mat == 0) out *= 0.18033688011112042f; // 1/sqrt(64)*log2(e)
          Cout[(((size_t)(mat * 4 + bb) * 12 + hh) * 2048 + s) * 64 + d] = (bf16)out;
        }
  }
}

// ---------------- GEMM (output proj): C[M][N] = A[M][K]*B[N][K]^T, fp32 out
// 64x128 tile, flat grid 768 with XCD remap (neutral, kept).
__global__ __launch_bounds__(256, 4)
void gemm_o(const bf16* __restrict__ A, const bf16* __restrict__ Bm,
            float* __restrict__ Cout) {
  constexpr int K = 768;
  __shared__ __align__(16) char As[2][64 * 64];  // 64 rows x 32 bf16, swizzled
  __shared__ __align__(16) char Bs[2][128 * 64]; // 128 rows x 32 bf16, swizzled
  const int tid = threadIdx.x;
  const int w = tid >> 6, lane = tid & 63;
  const int quad = lane >> 4, l15 = lane & 15;
  const int wrow = w >> 1, wcol = w & 1;
  const int f = blockIdx.x;                 // 0..767
  const int xcd = f & 7, j = f >> 3;        // j 0..95 = 16 mtiles x 6 ncols
  const int m0 = (xcd * 16 + j / 6) * 64;
  const int n0 = (j % 6) * 128;

  f32x4 acc[2][4];
#pragma unroll
  for (int mt = 0; mt < 2; ++mt)
#pragma unroll
    for (int nt = 0; nt < 4; ++nt) acc[mt][nt] = (f32x4){0.f, 0.f, 0.f, 0.f};

  auto stage = [&](int k0, int bufi) {
    {
      int L = tid;                    // A: 256 chunks (64 rows x 4)
      int r = L >> 2, cl = L & 3;
      int cg = cl ^ ((r >> 1) & 3);
      gl_lds16(A + (size_t)(m0 + r) * K + k0 + cg * 8, As[bufi] + (w * 64) * 16 + lane * 16);
    }
#pragma unroll
    for (int i = 0; i < 2; ++i) {     // B: 512 chunks (128 rows x 4)
      int L = i * 256 + tid;
      int r = L >> 2, cl = L & 3;
      int cg = cl ^ ((r >> 1) & 3);
      gl_lds16(Bm + (size_t)(n0 + r) * K + k0 + cg * 8, Bs[bufi] + (i * 256 + w * 64) * 16);
    }
  };

  stage(0, 0);
  int buf = 0;

  for (int k0 = 0; k0 < K; k0 += 32) {
    __syncthreads();
    if (k0 + 32 < K) stage(k0 + 32, buf ^ 1);
    const char* Ab = As[buf];
    const char* Bb = Bs[buf];

    bf16x8 af[2], bfr[4];
#pragma unroll
    for (int mt = 0; mt < 2; ++mt) {
      int r = wrow * 32 + mt * 16 + l15;
      int cl = quad ^ ((r >> 1) & 3);
      af[mt] = *(const bf16x8*)(Ab + r * 64 + cl * 16);
    }
#pragma unroll
    for (int nt = 0; nt < 4; ++nt) {
      int r = wcol * 64 + nt * 16 + l15;
      int cl = quad ^ ((r >> 1) & 3);
      bfr[nt] = *(const bf16x8*)(Bb + r * 64 + cl * 16);
    }
#pragma unroll
    for (int mt = 0; mt < 2; ++mt)
#pragma unroll
      for (int nt = 0; nt < 4; ++nt)
        acc[mt][nt] = mfma32(af[mt], bfr[nt], acc[mt][nt]);
    buf ^= 1;
  }

#pragma unroll
  for (int mt = 0; mt < 2; ++mt)
#pragma unroll
    for (int nt = 0; nt < 4; ++nt)
#pragma unroll
      for (int r = 0; r < 4; ++r) {
        int m = m0 + wrow * 32 + mt * 16 + quad * 4 + r;
        int n = n0 + wcol * 64 + nt * 16 + l15;
        Cout[(size_t)m * 768 + n] = acc[mt][nt][r];
      }
}

// ---------------- Flash attention (causal), 64 q/block, 2 waves ----
// R0 compute structure (proven local optimum) + XCD remap (neutral, kept).
// NEW: s_setprio(1) around the MFMA clusters — m191 measured +4-7% for
// attn's regime (independent small blocks, waves at different phases).
__global__ __launch_bounds__(128, 3)
void attn(const bf16* __restrict__ qkv, const bf16* __restrict__ vt,
          bf16* __restrict__ aout) {
  const int bx = blockIdx.x;                // 0..1535
  const int xcd = bx & 7, jb = bx >> 3;     // jb 0..191 = 32 qtiles x 6 bh
  const int qt = 31 - (jb / 6);             // longest-first within each XCD
  const int bh = xcd * 6 + (jb % 6);        // XCD-owned (b,h) group
  const int b = bh / 12, h = bh % 12;
  const int tid = threadIdx.x, w = tid >> 6, lane = tid & 63;
  const int quad = lane >> 4, l15 = lane & 15;
  const bf16* Q  = qkv + (size_t)bh * (2048 * 64);
  const bf16* Kp = qkv + (size_t)(48 + bh) * (2048 * 64);
  const bf16* Vt = vt + (size_t)bh * (64 * 2048);
  __shared__ __align__(16) char Ks[2][64 * 128]; // 64 keys x 64 d, swizzled chunks
  __shared__ __align__(16) char Vs[2][64 * 128]; // 64 d x 64 keys, swizzled chunks

  const int qbase = qt * 64 + w * 32; // wave's 32 queries: [qbase, qbase+32)
  bf16x8 qf[2][2];
#pragma unroll
  for (int j = 0; j < 2; ++j) {
    qf[j][0] = *(const bf16x8*)(Q + (size_t)(qbase + j * 16 + l15) * 64 + quad * 8);
    qf[j][1] = *(const bf16x8*)(Q + (size_t)(qbase + j * 16 + l15) * 64 + 32 + quad * 8);
  }

  float li[2] = {0.f, 0.f};
  f32x4 o[2][4];
#pragma unroll
  for (int j = 0; j < 2; ++j)
#pragma unroll
    for (int dt = 0; dt < 4; ++dt) o[j][dt] = (f32x4){0.f, 0.f, 0.f, 0.f};

  // stage K/V tile kb into LDS buffer bufi (async; drained by next barrier)
  auto stage = [&](int kb, int bufi) {
#pragma unroll
    for (int i = 0; i < 4; ++i) {
      int L = i * 128 + tid;          // chunk 0..511; lds dest = base + lane*16
      int r = L >> 3, cl = L & 7, cg = cl ^ (r & 7);
      gl_lds16(Kp + (size_t)(kb * 64 + r) * 64 + cg * 8, Ks[bufi] + L * 16);
      gl_lds16(Vt + (size_t)r * 2048 + kb * 64 + cg * 8, Vs[bufi] + L * 16);
    }
  };

  stage(0, 0);
  int buf = 0;

  for (int kb = 0; kb <= qt; ++kb) {
    __syncthreads();               // drains vmcnt: tile kb resident, buf^1 free
    if (kb < qt) stage(kb + 1, buf ^ 1);
    const char* Kb = Ks[buf];
    const char* Vb = Vs[buf];

    // S^T tiles: lane holds S[query=qbase+j*16+l15][key=kb*64+sk*16+quad*4+rr]
    float S[2][16];
    __builtin_amdgcn_s_setprio(1);
#pragma unroll
    for (int sk = 0; sk < 4; ++sk) {
      int r = sk * 16 + l15;
      int cl0 = quad ^ (r & 7);
      int cl1 = (4 + quad) ^ (r & 7);
      bf16x8 kf0 = *(const bf16x8*)(Kb + r * 128 + cl0 * 16);
      bf16x8 kf1 = *(const bf16x8*)(Kb + r * 128 + cl1 * 16);
#pragma unroll
      for (int j = 0; j < 2; ++j) {
        f32x4 st = (f32x4){0.f, 0.f, 0.f, 0.f};
        st = mfma32(kf0, qf[j][0], st);
        st = mfma32(kf1, qf[j][1], st);
#pragma unroll
        for (int rr = 0; rr < 4; ++rr) S[j][sk * 4 + rr] = st[rr]; // pre-scaled via Q
      }
    }
    __builtin_amdgcn_s_setprio(0);
    if (kb == qt) { // diagonal tile: mask future keys
#pragma unroll
      for (int j = 0; j < 2; ++j)
#pragma unroll
        for (int sk = 0; sk < 4; ++sk)
#pragma unroll
          for (int rr = 0; rr < 4; ++rr) {
            int key = kb * 64 + sk * 16 + quad * 4 + rr;
            if (key > qbase + j * 16 + l15) S[j][sk * 4 + rr] = -1e30f;
          }
    }

#if HAVE_MFMA16
    s16x4 pf[2][4];
#endif
#pragma unroll
    for (int j = 0; j < 2; ++j) {
      float rs = 0.f;
#pragma unroll
      for (int sk = 0; sk < 4; ++sk) {
        bf16x4 pb;
#pragma unroll
        for (int rr = 0; rr < 4; ++rr) {
          float p = EXP2(S[j][sk * 4 + rr]);
          rs += p;
          pb[rr] = (bf16)p;
#if !HAVE_MFMA16
          S[j][sk * 4 + rr] = p;
#endif
        }
#if HAVE_MFMA16
        pf[j][sk] = __builtin_bit_cast(s16x4, pb);
#else
        (void)pb;
#endif
      }
      rs += __shfl_xor(rs, 16);
      rs += __shfl_xor(rs, 32);
      li[j] += rs;
    }

#if HAVE_MFMA16
    // P C/D layout == A-operand layout of 16x16x16: direct feed; V-frag
    // LDS reads shared across both q-subtiles.
    __builtin_amdgcn_s_setprio(1);
#pragma unroll
    for (int sk = 0; sk < 4; ++sk)
#pragma unroll
      for (int dt = 0; dt < 4; ++dt) {
        int rr = dt * 16 + l15;                 // Vt row (d)
        int c = sk * 2 + (quad >> 1);           // 16B chunk along keys
        int cl = c ^ (rr & 7);
        s16x4 vf = *(const s16x4*)(Vb + rr * 128 + cl * 16 + (quad & 1) * 8);
        o[0][dt] = mfma16(pf[0][sk], vf, o[0][dt]);
        o[1][dt] = mfma16(pf[1][sk], vf, o[1][dt]);
      }
    __builtin_amdgcn_s_setprio(0);
#else
    // Fallback: assemble A-frags for 16x16x32 PV via shuffles
#pragma unroll
    for (int j = 0; j < 2; ++j)
#pragma unroll
      for (int kc = 0; kc < 2; ++kc) {
        bf16x8 af;
#pragma unroll
        for (int jj = 0; jj < 8; ++jj) {
          int sq = (quad & 1) * 2 + (jj >> 2);
          int src = sq * 16 + l15;
          float v0 = __shfl(S[j][kc * 8 + (jj & 3)], src);
          float v1 = __shfl(S[j][kc * 8 + 4 + (jj & 3)], src);
          af[jj] = (bf16)((quad < 2) ? v0 : v1);
        }
#pragma unroll
        for (int dt = 0; dt < 4; ++dt) {
          int rr = dt * 16 + l15;
          int c = kc * 4 + quad;
          int cl = c ^ (rr & 7);
          bf16x8 vf = *(const bf16x8*)(Vb + rr * 128 + cl * 16);
          o[j][dt] = mfma32(af, vf, o[j][dt]);
        }
      }
#endif
    buf ^= 1;
  }

#pragma unroll
  for (int j = 0; j < 2; ++j) {
    float lr[4];
#pragma unroll
    for (int rr = 0; rr < 4; ++rr)
      lr[rr] = __builtin_amdgcn_rcpf(__shfl(li[j], quad * 4 + rr));
#pragma unroll
    for (int dt = 0; dt < 4; ++dt)
#pragma unroll
      for (int rr = 0; rr < 4; ++rr) {
        int q = qbase + j * 16 + quad * 4 + rr;
        int n = h * 64 + dt * 16 + l15;
        aout[((size_t)b * 2048 + q) * 768 + n] = (bf16)(o[j][dt][rr] * lr[rr]);
      }
  }
}

// ---------------- launch ----------------
extern "C" void kernel_launch(void* const* d_in, const int* in_sizes, int n_in,
                              void* d_out, int out_size, void* d_ws, size_t ws_size,
                              hipStream_t stream) {
  const float* x    = (const float*)d_in[0];
  const float* wqkv = (const float*)d_in[1];
  const float* wo   = (const float*)d_in[2];
  const int* tpos   = (const int*)d_in[3];
  const int* thetap = (const int*)d_in[5];

  char* ws = (char*)d_ws;
  // ws layout (bytes):
  bf16* xb    = (bf16*)(ws);              // 12,582,912  (reused as attn out)
  bf16* wqkvb = (bf16*)(ws + 12582912);   //  3,538,944
  bf16* wob   = (bf16*)(ws + 16121856);   //  1,179,648
  bf16* qkv   = (bf16*)(ws + 17301504);   // 37,748,736  [3][b][h][s][64] (mat==2 slot unused)
  bf16* vtb   = (bf16*)(ws + 55050240);   // 12,582,912  [b][h][64][2048]
  float2* tab = (float2*)(ws + 42467328); //  2,097,152  trig table, inside unused qkv mat==2 slot

  prep<<<9472, 256, 0, stream>>>(x, xb, wqkv, wqkvb, wo, wob, tpos, thetap, tab);
  gemm_qkv<<<dim3(64, 18), 256, 0, stream>>>(xb, wqkvb, qkv, vtb, tab);
  attn<<<1536, 128, 0, stream>>>(qkv, vtb, xb);
  gemm_o<<<768, 256, 0, stream>>>(xb, wob, (float*)d_out);
}

// Round 11
// 205.004 us; speedup vs baseline: 1.1201x; 1.0174x over previous
//
#include <hip/hip_runtime.h>
#include <hip/hip_bf16.h>

// Problem dims (hardcoded): B=4, S=2048, D=768, H=12, hd=64
//
// Accounting (R9): total 208.6 ~= gemm_qkv(~51, V-transpose epilogue win)
// + attn(63.8) + gemm_o(~23-40) + prep(~10) + fixed(~45-60).
// R9 lesson: attn setprio cost ~4us — our attn has 2 waves in per-tile
// barrier LOCKSTEP, i.e. the m190 (GEMM-negative) regime, not m191's
// independent-block regime. Removed (this round = R10 resubmit; R10 bench
// was an infra failure, no data).
// Proven-and-kept: gemm_qkv 128x128 2-buffer + padded-LDS V-transpose
// coalesced epilogue + launch_bounds(256,4); attn R0 compute structure
// (R1/R4 structure changes regressed) + neutral XCD remap; gemm_o 64x128.
typedef __bf16 bf16;
typedef __bf16 bf16x8 __attribute__((ext_vector_type(8)));
typedef __bf16 bf16x4 __attribute__((ext_vector_type(4)));
typedef short  s16x4  __attribute__((ext_vector_type(4)));
typedef float  f32x4  __attribute__((ext_vector_type(4)));

#if defined(__has_builtin)
#if __has_builtin(__builtin_amdgcn_mfma_f32_16x16x16bf16_1k)
#define HAVE_MFMA16 1
#endif
#if __has_builtin(__builtin_amdgcn_exp2f)
#define EXP2(x) __builtin_amdgcn_exp2f(x)
#else
#define EXP2(x) exp2f(x)
#endif
#else
#define EXP2(x) exp2f(x)
#endif

__device__ __forceinline__ void gl_lds16(const void* g, void* l) {
  __builtin_amdgcn_global_load_lds(
      (__attribute__((address_space(1))) const void*)g,
      (__attribute__((address_space(3))) void*)l, 16, 0, 0);
}

__device__ __forceinline__ f32x4 mfma32(bf16x8 a, bf16x8 b, f32x4 c) {
  return __builtin_amdgcn_mfma_f32_16x16x32_bf16(a, b, c, 0, 0, 0);
}
#if HAVE_MFMA16
__device__ __forceinline__ f32x4 mfma16(s16x4 a, s16x4 b, f32x4 c) {
  return __builtin_amdgcn_mfma_f32_16x16x16bf16_1k(a, b, c, 0, 0, 0);
}
#endif

// ---------------- prep: fp32->bf16 convert (x, W_QKV, W_O) + RoPE trig table
// tab[b*2048+s][d2] = (cos, sin) of pos*theta^(-d2/32).
__global__ void prep(const float* __restrict__ a, bf16* __restrict__ da,
                     const float* __restrict__ b, bf16* __restrict__ db,
                     const float* __restrict__ c, bf16* __restrict__ dc,
                     const int* __restrict__ tpos, const int* __restrict__ thetap,
                     float2* __restrict__ tab) {
  int bx = blockIdx.x;
  if (bx >= 8448) {                       // trig table blocks
    int i = (bx - 8448) * 256 + threadIdx.x; // < 4*2048*32 = 262144
    int d2 = i & 31;
    int bs = i >> 5;                      // b*2048+s
    float lt = log2f((float)(*thetap));
    float fr = exp2f(-(float)d2 * (1.0f / 32.0f) * lt); // theta^(-d2/32)
    float ang = (float)tpos[bs] * fr;
    float sn, cs;
    sincosf(ang, &sn, &cs);
    tab[i] = make_float2(cs, sn);
    return;
  }
  const float* s; bf16* d; int i;
  if (bx < 6144)      { s = a; d = da; i = bx * 256 + threadIdx.x; }
  else if (bx < 7872) { s = b; d = db; i = (bx - 6144) * 256 + threadIdx.x; }
  else                { s = c; d = dc; i = (bx - 7872) * 256 + threadIdx.x; }
  float4 v = ((const float4*)s)[i];
  bf16x4 o;
  o[0] = (bf16)v.x; o[1] = (bf16)v.y; o[2] = (bf16)v.z; o[3] = (bf16)v.w;
  ((bf16x4*)d)[i] = o;
}

// ---------------- GEMM (QKV): C = A[M][K] * B[N][K]^T, K=768, 128x128 tile
// 2-buffer skeleton, grid (64,18) default dispatch, launch_bounds(256,4).
// mat==2 (V) blocks transpose their tile through padded LDS and store
// Vout[b][h][64][2048] COALESCED (R9: −15us vs 2-byte scattered stores).
// Epilogue q,k: scatter to qkv[mat][b][h][s][64] WITH fused RoPE
// (pair partner via __shfl_xor(v,1)); Q scaled by 1/sqrt(64)*log2(e).
__global__ __launch_bounds__(256, 4)
void gemm_qkv(const bf16* __restrict__ A, const bf16* __restrict__ Bm,
              bf16* __restrict__ Cout, bf16* __restrict__ Vout,
              const float2* __restrict__ tab) {
  constexpr int K = 768;
  // [2 bufs][A 8KB | B 8KB]; also reused (17KB span) by the V-transpose.
  __shared__ __align__(16) char SM[2][16384];
  const int tid = threadIdx.x;
  const int w = tid >> 6, lane = tid & 63;
  const int quad = lane >> 4, l15 = lane & 15;
  const int wrow = w >> 1, wcol = w & 1;
  const int m0 = blockIdx.x * 128, n0 = blockIdx.y * 128;

  f32x4 acc[4][4];
#pragma unroll
  for (int mt = 0; mt < 4; ++mt)
#pragma unroll
    for (int nt = 0; nt < 4; ++nt) acc[mt][nt] = (f32x4){0.f, 0.f, 0.f, 0.f};

  auto stage = [&](int k0, int bufi) {
#pragma unroll
    for (int i = 0; i < 2; ++i) {
      int L = i * 256 + tid;          // chunk index 0..511
      int r = L >> 2, cl = L & 3;
      int cg = cl ^ ((r >> 1) & 3);   // swizzle: conflict-free frag reads
      gl_lds16(A + (size_t)(m0 + r) * K + k0 + cg * 8, SM[bufi] + (i * 256 + w * 64) * 16);
      gl_lds16(Bm + (size_t)(n0 + r) * K + k0 + cg * 8, SM[bufi] + 8192 + (i * 256 + w * 64) * 16);
    }
  };

  stage(0, 0);
  int buf = 0;

  for (int k0 = 0; k0 < K; k0 += 32) {
    __syncthreads();                 // drains stage(k0) (issued last iter)
    if (k0 + 32 < K) stage(k0 + 32, buf ^ 1);
    const char* Ab = SM[buf];
    const char* Bb = SM[buf] + 8192;

    bf16x8 af[4], bfr[4];
#pragma unroll
    for (int mt = 0; mt < 4; ++mt) {
      int r = wrow * 64 + mt * 16 + l15;
      int cl = quad ^ ((r >> 1) & 3);
      af[mt] = *(const bf16x8*)(Ab + r * 64 + cl * 16);
    }
#pragma unroll
    for (int nt = 0; nt < 4; ++nt) {
      int r = wcol * 64 + nt * 16 + l15;
      int cl = quad ^ ((r >> 1) & 3);
      bfr[nt] = *(const bf16x8*)(Bb + r * 64 + cl * 16);
    }
#pragma unroll
    for (int mt = 0; mt < 4; ++mt)
#pragma unroll
      for (int nt = 0; nt < 4; ++nt)
        acc[mt][nt] = mfma32(af[mt], bfr[nt], acc[mt][nt]);
    buf ^= 1;
  }

  const int mat = n0 / 768;            // block-uniform (768 % 128 == 0)
  if (mat == 2) {
    // ---- V: transpose via LDS, coalesced Vout[b][h][64][2048] stores ----
    constexpr int PITCH = 136;         // bf16; 16B-aligned rows, 2-way-free banks
    bf16* T = (bf16*)&SM[0][0];
    const int bb = m0 >> 11, s0 = m0 & 2047;
    const int hh0 = (n0 % 768) >> 6;   // first of the 2 heads this block covers
#pragma unroll
    for (int hh = 0; hh < 2; ++hh) {
      __syncthreads();                 // LDS free (K-loop / previous head done)
      if (wcol == hh) {                // this wave's acc holds head hh
#pragma unroll
        for (int mt = 0; mt < 4; ++mt)
#pragma unroll
          for (int nt = 0; nt < 4; ++nt)
#pragma unroll
            for (int r = 0; r < 4; ++r) {
              int s_local = wrow * 64 + mt * 16 + quad * 4 + r; // 0..127
              int d_local = nt * 16 + l15;                      // 0..63
              T[d_local * PITCH + s_local] = (bf16)acc[mt][nt][r];
            }
      }
      __syncthreads();
      // read out rows, store coalesced: thread t -> row t>>2, 64B chunk t&3
      {
        int row = tid >> 2, chunk = tid & 3;
        const bf16* src = T + row * PITCH + chunk * 32;
        bf16x8 v0 = ((const bf16x8*)src)[0];
        bf16x8 v1 = ((const bf16x8*)src)[1];
        bf16x8 v2 = ((const bf16x8*)src)[2];
        bf16x8 v3 = ((const bf16x8*)src)[3];
        bf16* dst = Vout + (((size_t)(bb * 12 + hh0 + hh) * 64 + row) * 2048) + s0 + chunk * 32;
        ((bf16x8*)dst)[0] = v0;
        ((bf16x8*)dst)[1] = v1;
        ((bf16x8*)dst)[2] = v2;
        ((bf16x8*)dst)[3] = v3;
      }
    }
  } else {
    // ---- Q/K: RoPE-fused scatter to qkv[mat][b][h][s][64] ----
#pragma unroll
    for (int mt = 0; mt < 4; ++mt)
#pragma unroll
      for (int nt = 0; nt < 4; ++nt)
#pragma unroll
        for (int r = 0; r < 4; ++r) {
          int m = m0 + wrow * 64 + mt * 16 + quad * 4 + r;
          int n = n0 + wcol * 64 + nt * 16 + l15;
          float v = acc[mt][nt][r];
          int rem = n % 768;
          int hh = rem >> 6, d = rem & 63;
          int bb = m >> 11, s = m & 2047;
          // RoPE: pair partner lives in the adjacent lane (d^1).
          float partner = __shfl_xor(v, 1);
          float2 t = tab[((size_t)m << 5) + ((rem >> 1) & 31)]; // (cos, sin)
          float out = v * t.x + ((n & 1) ? partner : -partner) * t.y;
          if (mat == 0) out *= 0.18033688011112042f; // 1/sqrt(64)*log2(e)
          Cout[(((size_t)(mat * 4 + bb) * 12 + hh) * 2048 + s) * 64 + d] = (bf16)out;
        }
  }
}

// ---------------- GEMM (output proj): C[M][N] = A[M][K]*B[N][K]^T, fp32 out
// 64x128 tile, flat grid 768 with XCD remap (neutral, kept).
__global__ __launch_bounds__(256, 4)
void gemm_o(const bf16* __restrict__ A, const bf16* __restrict__ Bm,
            float* __restrict__ Cout) {
  constexpr int K = 768;
  __shared__ __align__(16) char As[2][64 * 64];  // 64 rows x 32 bf16, swizzled
  __shared__ __align__(16) char Bs[2][128 * 64]; // 128 rows x 32 bf16, swizzled
  const int tid = threadIdx.x;
  const int w = tid >> 6, lane = tid & 63;
  const int quad = lane >> 4, l15 = lane & 15;
  const int wrow = w >> 1, wcol = w & 1;
  const int f = blockIdx.x;                 // 0..767
  const int xcd = f & 7, j = f >> 3;        // j 0..95 = 16 mtiles x 6 ncols
  const int m0 = (xcd * 16 + j / 6) * 64;
  const int n0 = (j % 6) * 128;

  f32x4 acc[2][4];
#pragma unroll
  for (int mt = 0; mt < 2; ++mt)
#pragma unroll
    for (int nt = 0; nt < 4; ++nt) acc[mt][nt] = (f32x4){0.f, 0.f, 0.f, 0.f};

  auto stage = [&](int k0, int bufi) {
    {
      int L = tid;                    // A: 256 chunks (64 rows x 4)
      int r = L >> 2, cl = L & 3;
      int cg = cl ^ ((r >> 1) & 3);
      gl_lds16(A + (size_t)(m0 + r) * K + k0 + cg * 8, As[bufi] + (w * 64) * 16 + lane * 16);
    }
#pragma unroll
    for (int i = 0; i < 2; ++i) {     // B: 512 chunks (128 rows x 4)
      int L = i * 256 + tid;
      int r = L >> 2, cl = L & 3;
      int cg = cl ^ ((r >> 1) & 3);
      gl_lds16(Bm + (size_t)(n0 + r) * K + k0 + cg * 8, Bs[bufi] + (i * 256 + w * 64) * 16);
    }
  };

  stage(0, 0);
  int buf = 0;

  for (int k0 = 0; k0 < K; k0 += 32) {
    __syncthreads();
    if (k0 + 32 < K) stage(k0 + 32, buf ^ 1);
    const char* Ab = As[buf];
    const char* Bb = Bs[buf];

    bf16x8 af[2], bfr[4];
#pragma unroll
    for (int mt = 0; mt < 2; ++mt) {
      int r = wrow * 32 + mt * 16 + l15;
      int cl = quad ^ ((r >> 1) & 3);
      af[mt] = *(const bf16x8*)(Ab + r * 64 + cl * 16);
    }
#pragma unroll
    for (int nt = 0; nt < 4; ++nt) {
      int r = wcol * 64 + nt * 16 + l15;
      int cl = quad ^ ((r >> 1) & 3);
      bfr[nt] = *(const bf16x8*)(Bb + r * 64 + cl * 16);
    }
#pragma unroll
    for (int mt = 0; mt < 2; ++mt)
#pragma unroll
      for (int nt = 0; nt < 4; ++nt)
        acc[mt][nt] = mfma32(af[mt], bfr[nt], acc[mt][nt]);
    buf ^= 1;
  }

#pragma unroll
  for (int mt = 0; mt < 2; ++mt)
#pragma unroll
    for (int nt = 0; nt < 4; ++nt)
#pragma unroll
      for (int r = 0; r < 4; ++r) {
        int m = m0 + wrow * 32 + mt * 16 + quad * 4 + r;
        int n = n0 + wcol * 64 + nt * 16 + l15;
        Cout[(size_t)m * 768 + n] = acc[mt][nt][r];
      }
}

// ---------------- Flash attention (causal), 64 q/block, 2 waves ----
// R0 compute structure (proven local optimum) + XCD remap (neutral, kept).
// setprio REMOVED (R9: cost ~4us — 2 lockstep waves/block = m190 regime).
__global__ __launch_bounds__(128, 3)
void attn(const bf16* __restrict__ qkv, const bf16* __restrict__ vt,
          bf16* __restrict__ aout) {
  const int bx = blockIdx.x;                // 0..1535
  const int xcd = bx & 7, jb = bx >> 3;     // jb 0..191 = 32 qtiles x 6 bh
  const int qt = 31 - (jb / 6);             // longest-first within each XCD
  const int bh = xcd * 6 + (jb % 6);        // XCD-owned (b,h) group
  const int b = bh / 12, h = bh % 12;
  const int tid = threadIdx.x, w = tid >> 6, lane = tid & 63;
  const int quad = lane >> 4, l15 = lane & 15;
  const bf16* Q  = qkv + (size_t)bh * (2048 * 64);
  const bf16* Kp = qkv + (size_t)(48 + bh) * (2048 * 64);
  const bf16* Vt = vt + (size_t)bh * (64 * 2048);
  __shared__ __align__(16) char Ks[2][64 * 128]; // 64 keys x 64 d, swizzled chunks
  __shared__ __align__(16) char Vs[2][64 * 128]; // 64 d x 64 keys, swizzled chunks

  const int qbase = qt * 64 + w * 32; // wave's 32 queries: [qbase, qbase+32)
  bf16x8 qf[2][2];
#pragma unroll
  for (int j = 0; j < 2; ++j) {
    qf[j][0] = *(const bf16x8*)(Q + (size_t)(qbase + j * 16 + l15) * 64 + quad * 8);
    qf[j][1] = *(const bf16x8*)(Q + (size_t)(qbase + j * 16 + l15) * 64 + 32 + quad * 8);
  }

  float li[2] = {0.f, 0.f};
  f32x4 o[2][4];
#pragma unroll
  for (int j = 0; j < 2; ++j)
#pragma unroll
    for (int dt = 0; dt < 4; ++dt) o[j][dt] = (f32x4){0.f, 0.f, 0.f, 0.f};

  // stage K/V tile kb into LDS buffer bufi (async; drained by next barrier)
  auto stage = [&](int kb, int bufi) {
#pragma unroll
    for (int i = 0; i < 4; ++i) {
      int L = i * 128 + tid;          // chunk 0..511; lds dest = base + lane*16
      int r = L >> 3, cl = L & 7, cg = cl ^ (r & 7);
      gl_lds16(Kp + (size_t)(kb * 64 + r) * 64 + cg * 8, Ks[bufi] + L * 16);
      gl_lds16(Vt + (size_t)r * 2048 + kb * 64 + cg * 8, Vs[bufi] + L * 16);
    }
  };

  stage(0, 0);
  int buf = 0;

  for (int kb = 0; kb <= qt; ++kb) {
    __syncthreads();               // drains vmcnt: tile kb resident, buf^1 free
    if (kb < qt) stage(kb + 1, buf ^ 1);
    const char* Kb = Ks[buf];
    const char* Vb = Vs[buf];

    // S^T tiles: lane holds S[query=qbase+j*16+l15][key=kb*64+sk*16+quad*4+rr]
    float S[2][16];
#pragma unroll
    for (int sk = 0; sk < 4; ++sk) {
      int r = sk * 16 + l15;
      int cl0 = quad ^ (r & 7);
      int cl1 = (4 + quad) ^ (r & 7);
      bf16x8 kf0 = *(const bf16x8*)(Kb + r * 128 + cl0 * 16);
      bf16x8 kf1 = *(const bf16x8*)(Kb + r * 128 + cl1 * 16);
#pragma unroll
      for (int j = 0; j < 2; ++j) {
        f32x4 st = (f32x4){0.f, 0.f, 0.f, 0.f};
        st = mfma32(kf0, qf[j][0], st);
        st = mfma32(kf1, qf[j][1], st);
#pragma unroll
        for (int rr = 0; rr < 4; ++rr) S[j][sk * 4 + rr] = st[rr]; // pre-scaled via Q
      }
    }
    if (kb == qt) { // diagonal tile: mask future keys
#pragma unroll
      for (int j = 0; j < 2; ++j)
#pragma unroll
        for (int sk = 0; sk < 4; ++sk)
#pragma unroll
          for (int rr = 0; rr < 4; ++rr) {
            int key = kb * 64 + sk * 16 + quad * 4 + rr;
            if (key > qbase + j * 16 + l15) S[j][sk * 4 + rr] = -1e30f;
          }
    }

#if HAVE_MFMA16
    s16x4 pf[2][4];
#endif
#pragma unroll
    for (int j = 0; j < 2; ++j) {
      float rs = 0.f;
#pragma unroll
      for (int sk = 0; sk < 4; ++sk) {
        bf16x4 pb;
#pragma unroll
        for (int rr = 0; rr < 4; ++rr) {
          float p = EXP2(S[j][sk * 4 + rr]);
          rs += p;
          pb[rr] = (bf16)p;
#if !HAVE_MFMA16
          S[j][sk * 4 + rr] = p;
#endif
        }
#if HAVE_MFMA16
        pf[j][sk] = __builtin_bit_cast(s16x4, pb);
#else
        (void)pb;
#endif
      }
      rs += __shfl_xor(rs, 16);
      rs += __shfl_xor(rs, 32);
      li[j] += rs;
    }

#if HAVE_MFMA16
    // P C/D layout == A-operand layout of 16x16x16: direct feed; V-frag
    // LDS reads shared across both q-subtiles.
#pragma unroll
    for (int sk = 0; sk < 4; ++sk)
#pragma unroll
      for (int dt = 0; dt < 4; ++dt) {
        int rr = dt * 16 + l15;                 // Vt row (d)
        int c = sk * 2 + (quad >> 1);           // 16B chunk along keys
        int cl = c ^ (rr & 7);
        s16x4 vf = *(const s16x4*)(Vb + rr * 128 + cl * 16 + (quad & 1) * 8);
        o[0][dt] = mfma16(pf[0][sk], vf, o[0][dt]);
        o[1][dt] = mfma16(pf[1][sk], vf, o[1][dt]);
      }
#else
    // Fallback: assemble A-frags for 16x16x32 PV via shuffles
#pragma unroll
    for (int j = 0; j < 2; ++j)
#pragma unroll
      for (int kc = 0; kc < 2; ++kc) {
        bf16x8 af;
#pragma unroll
        for (int jj = 0; jj < 8; ++jj) {
          int sq = (quad & 1) * 2 + (jj >> 2);
          int src = sq * 16 + l15;
          float v0 = __shfl(S[j][kc * 8 + (jj & 3)], src);
          float v1 = __shfl(S[j][kc * 8 + 4 + (jj & 3)], src);
          af[jj] = (bf16)((quad < 2) ? v0 : v1);
        }
#pragma unroll
        for (int dt = 0; dt < 4; ++dt) {
          int rr = dt * 16 + l15;
          int c = kc * 4 + quad;
          int cl = c ^ (rr & 7);
          bf16x8 vf = *(const bf16x8*)(Vb + rr * 128 + cl * 16);
          o[j][dt] = mfma32(af, vf, o[j][dt]);
        }
      }
#endif
    buf ^= 1;
  }

#pragma unroll
  for (int j = 0; j < 2; ++j) {
    float lr[4];
#pragma unroll
    for (int rr = 0; rr < 4; ++rr)
      lr[rr] = __builtin_amdgcn_rcpf(__shfl(li[j], quad * 4 + rr));
#pragma unroll
    for (int dt = 0; dt < 4; ++dt)
#pragma unroll
      for (int rr = 0; rr < 4; ++rr) {
        int q = qbase + j * 16 + quad * 4 + rr;
        int n = h * 64 + dt * 16 + l15;
        aout[((size_t)b * 2048 + q) * 768 + n] = (bf16)(o[j][dt][rr] * lr[rr]);
      }
  }
}

// ---------------- launch ----------------
extern "C" void kernel_launch(void* const* d_in, const int* in_sizes, int n_in,
                              void* d_out, int out_size, void* d_ws, size_t ws_size,
                              hipStream_t stream) {
  const float* x    = (const float*)d_in[0];
  const float* wqkv = (const float*)d_in[1];
  const float* wo   = (const float*)d_in[2];
  const int* tpos   = (const int*)d_in[3];
  const int* thetap = (const int*)d_in[5];

  char* ws = (char*)d_ws;
  // ws layout (bytes):
  bf16* xb    = (bf16*)(ws);              // 12,582,912  (reused as attn out)
  bf16* wqkvb = (bf16*)(ws + 12582912);   //  3,538,944
  bf16* wob   = (bf16*)(ws + 16121856);   //  1,179,648
  bf16* qkv   = (bf16*)(ws + 17301504);   // 37,748,736  [3][b][h][s][64] (mat==2 slot unused)
  bf16* vtb   = (bf16*)(ws + 55050240);   // 12,582,912  [b][h][64][2048]
  float2* tab = (float2*)(ws + 42467328); //  2,097,152  trig table, inside unused qkv mat==2 slot

  prep<<<9472, 256, 0, stream>>>(x, xb, wqkv, wqkvb, wo, wob, tpos, thetap, tab);
  gemm_qkv<<<dim3(64, 18), 256, 0, stream>>>(xb, wqkvb, qkv, vtb, tab);
  attn<<<1536, 128, 0, stream>>>(qkv, vtb, xb);
  gemm_o<<<768, 256, 0, stream>>>(xb, wob, (float*)d_out);
}